// Round 9
// baseline (643.761 us; speedup 1.0000x reference)
//
#include <hip/hip_runtime.h>

typedef __bf16 bf16;
typedef __bf16 bf16x8 __attribute__((ext_vector_type(8)));
typedef __bf16 bf16x4 __attribute__((ext_vector_type(4)));
typedef float f32x4 __attribute__((ext_vector_type(4)));

#define B_ 4
#define N_ 2048
#define C_ 1024
#define H_ 16
#define HKV_ 4
#define D_ 64

// fold: 1.5 (qk_gain) * 0.125 (1/sqrt(64)) * log2(e)  -> use exp2f in softmax
#define QSCALE 0.2705053201666806f
#define NEGINF (-1.0e30f)

// ---------------------------------------------------------------------------
// GEMM: C[M][.] = A[M][K] * B[K][.].
//   A: row-major, dtype AT (float -> converted to bf16 during LDS staging,
//      bf16 -> copied directly).
//   B: row-major FP32 with row stride bn_stride; transposed AND converted to
//      bf16 during LDS staging into Bs[n][k].
//   C: dtype OT (bf16 for intermediates, float for the final output),
//      written at Cmat[row*ostride + col0 + n0 + col].
// 128x128 tile, BK=64, 4 waves x (64x64 quadrant) via 4x4 16x16x32 MFMAs.
// LDS stride 72 elems (144 B): ds_read_b128 16B-aligned, 2-way-conflict free.
template <typename AT, typename OT>
__global__ __launch_bounds__(256) void gemm_any(const AT* __restrict__ A,
                                                const float* __restrict__ B,
                                                OT* __restrict__ Cmat,
                                                int M, int K, int bn_stride,
                                                int ostride, int col0) {
  __shared__ __align__(16) bf16 As[128 * 72];
  __shared__ __align__(16) bf16 Bs[128 * 72];
  int m0 = blockIdx.x * 128, n0 = blockIdx.y * 128;
  int tid = threadIdx.x;
  int wave = tid >> 6, lane = tid & 63;
  int quad = lane >> 4, lr = lane & 15;
  int wr = (wave >> 1) * 64, wc = (wave & 1) * 64;

  f32x4 acc[4][4];
  const f32x4 z = {0.f, 0.f, 0.f, 0.f};
#pragma unroll
  for (int i = 0; i < 4; ++i)
#pragma unroll
    for (int j = 0; j < 4; ++j) acc[i][j] = z;

  for (int k0 = 0; k0 < K; k0 += 64) {
    __syncthreads();
    // A: 128 rows x 64 k into As[row][k]
    if constexpr (sizeof(AT) == 4) {
#pragma unroll
      for (int i = 0; i < 8; ++i) {
        int c = tid + i * 256;          // 2048 float4-chunks
        int row = c >> 4, off4 = (c & 15) * 4;
        f32x4 av = *(const f32x4*)(A + (size_t)(m0 + row) * K + k0 + off4);
        bf16x4 a16;
#pragma unroll
        for (int j = 0; j < 4; ++j) a16[j] = (bf16)av[j];
        *(bf16x4*)(As + row * 72 + off4) = a16;
      }
    } else {
#pragma unroll
      for (int i = 0; i < 4; ++i) {
        int c = tid + i * 256;          // 1024 bf16x8-chunks
        int row = c >> 3, off = (c & 7) * 8;
        *(bf16x8*)(As + row * 72 + off) =
            *(const bf16x8*)(A + (size_t)(m0 + row) * K + k0 + off);
      }
    }
    // B: 64 k-rows x 128 n (fp32), transposed+converted into Bs[n][k]
#pragma unroll
    for (int i = 0; i < 8; ++i) {
      int c = tid + i * 256;            // 2048 float4-chunks
      int k = c >> 5, n4 = (c & 31) * 4;
      f32x4 bv = *(const f32x4*)(B + (size_t)(k0 + k) * bn_stride + n0 + n4);
#pragma unroll
      for (int j = 0; j < 4; ++j) Bs[(n4 + j) * 72 + k] = (bf16)bv[j];
    }
    __syncthreads();
#pragma unroll
    for (int kx = 0; kx < 2; ++kx) {
      bf16x8 af[4], bfr[4];
#pragma unroll
      for (int t = 0; t < 4; ++t) {
        af[t] = *(const bf16x8*)(As + (wr + t * 16 + lr) * 72 + kx * 32 + quad * 8);
        bfr[t] = *(const bf16x8*)(Bs + (wc + t * 16 + lr) * 72 + kx * 32 + quad * 8);
      }
#pragma unroll
      for (int rt = 0; rt < 4; ++rt)
#pragma unroll
        for (int ct = 0; ct < 4; ++ct)
          acc[rt][ct] = __builtin_amdgcn_mfma_f32_16x16x32_bf16(af[rt], bfr[ct],
                                                                acc[rt][ct], 0, 0, 0);
    }
  }
#pragma unroll
  for (int rt = 0; rt < 4; ++rt)
#pragma unroll
    for (int ct = 0; ct < 4; ++ct)
#pragma unroll
      for (int r = 0; r < 4; ++r) {
        int row = m0 + wr + rt * 16 + quad * 4 + r;
        int col = col0 + n0 + wc + ct * 16 + lr;
        Cmat[(size_t)row * ostride + col] = (OT)acc[rt][ct][r];
      }
}

// ---------------------------------------------------------------------------
// V transpose: kv [B*N][512] (v = cols 256..511, head hkv at 256+hkv*64)
//           -> vt [B][HKV][D][N]
__global__ __launch_bounds__(256) void transpose_v(const bf16* __restrict__ kv,
                                                   bf16* __restrict__ vt) {
  __shared__ __align__(16) bf16 lds[64 * 72];
  int nt = blockIdx.x;  // token tile (64 tokens)
  int bh = blockIdx.y;  // b*4 + hkv
  int b = bh >> 2, hkv = bh & 3;
  int tid = threadIdx.x;
#pragma unroll
  for (int i = 0; i < 2; ++i) {
    int c = tid + i * 256;
    int tok = c >> 3, off = (c & 7) * 8;
    *(bf16x8*)(lds + tok * 72 + off) =
        *(const bf16x8*)(kv + (size_t)(b * N_ + nt * 64 + tok) * 512 + 256 + hkv * 64 + off);
  }
  __syncthreads();
#pragma unroll
  for (int i = 0; i < 2; ++i) {
    int c = tid + i * 256;
    int d = c >> 3, toff = (c & 7) * 8;
    bf16x8 tv;
#pragma unroll
    for (int j = 0; j < 8; ++j) tv[j] = lds[(toff + j) * 72 + d];
    *(bf16x8*)(vt + ((size_t)bh * 64 + d) * N_ + nt * 64 + toff) = tv;
  }
}

// ---------------------------------------------------------------------------
// Per-head RMSNorm + RoPE, in place (bf16 data, fp32 math). One wave per
// (token, head) 64-vector. q heads get folded QSCALE; k heads don't.
// eps = fp32 machine eps (reference x.dtype is float32).
__global__ __launch_bounds__(256) void norm_rope(bf16* __restrict__ q,
                                                 bf16* __restrict__ kv) {
  int wave = threadIdx.x >> 6, lane = threadIdx.x & 63;
  int hid = blockIdx.x * 4 + wave;  // 0 .. B*N*20-1
  int t = hid / 20;                 // token index (b*N+n)
  int sub = hid - t * 20;           // 0..15 = q head, 16..19 = k head
  int n = t & (N_ - 1);
  bf16* ptr;
  float oscale;
  if (sub < 16) {
    ptr = q + ((size_t)t * 16 + sub) * 64;
    oscale = QSCALE;
  } else {
    ptr = kv + (size_t)t * 512 + (sub - 16) * 64;
    oscale = 1.0f;
  }
  float x = (float)ptr[lane];
  float ss = x * x;
  ss += __shfl_xor(ss, 1);
  ss += __shfl_xor(ss, 2);
  ss += __shfl_xor(ss, 4);
  ss += __shfl_xor(ss, 8);
  ss += __shfl_xor(ss, 16);
  ss += __shfl_xor(ss, 32);
  float rn = rsqrtf(ss * (1.0f / 64.0f) + 1.1920929e-07f);
  float xn = x * rn;
  float pr = __shfl_xor(xn, 32);
  float rot = (lane < 32) ? -pr : pr;
  // inv_freq[i] = 10000^(-i/32) = 2^(-i * log2(10000)/32)
  float ang = (float)n * exp2f(-0.41524101186092029f * (float)(lane & 31));
  float sv, cv;
  sincosf(ang, &sv, &cv);
  ptr[lane] = (bf16)((xn * cv + rot * sv) * oscale);
}

// ---------------------------------------------------------------------------
// Causal flash attention with GQA. Block = 128 q rows of one (b,h); 4 waves,
// each owns 32 q rows. K/V tiles of 64 keys. Online softmax in MFMA C-layout;
// P round-trips wave-private LDS rows to reach the A-operand layout for PV.
// OUTPUT IS WRITTEN IN PLACE into q: each block reads only its own disjoint
// (rows, head) slice of q at kernel start and writes only that slice.
__global__ __launch_bounds__(256) void attn(bf16* __restrict__ q,
                                            const bf16* __restrict__ kv,
                                            const bf16* __restrict__ vt) {
  __shared__ __align__(16) bf16 Ks[64 * 72];   // [key][d]
  __shared__ __align__(16) bf16 Vs[64 * 72];   // [d][key]
  __shared__ __align__(16) bf16 Ps[128 * 72];  // [q-row][key], wave-private rows
  int qt = blockIdx.x, h = blockIdx.y, b = blockIdx.z;
  int hkv = h >> 2;
  int tid = threadIdx.x;
  int wave = tid >> 6, lane = tid & 63;
  int quad = lane >> 4, lr = lane & 15;
  int qrow0 = qt * 128 + wave * 32;

  // Preload Q fragments (A-layout): rows qrow0 + rt*16 + lr, k = kx*32+quad*8
  bf16x8 qf[2][2];
#pragma unroll
  for (int rt = 0; rt < 2; ++rt)
#pragma unroll
    for (int kx = 0; kx < 2; ++kx)
      qf[rt][kx] = *(const bf16x8*)(
          q + ((size_t)(b * N_ + qrow0 + rt * 16 + lr) * H_ + h) * D_ + kx * 32 + quad * 8);

  f32x4 acc[2][4];
  const f32x4 z = {0.f, 0.f, 0.f, 0.f};
  float mrow[2][4], lrow[2][4];
#pragma unroll
  for (int rt = 0; rt < 2; ++rt) {
#pragma unroll
    for (int dt = 0; dt < 4; ++dt) acc[rt][dt] = z;
#pragma unroll
    for (int r = 0; r < 4; ++r) {
      mrow[rt][r] = NEGINF;
      lrow[rt][r] = 0.f;
    }
  }

  int nkt = qt * 2 + 2;
  for (int kt = 0; kt < nkt; ++kt) {
    __syncthreads();
    // Stage K (row-major [key][d]) and V^T ([d][key]) tiles
#pragma unroll
    for (int i = 0; i < 2; ++i) {
      int c = tid + i * 256;
      int row = c >> 3, off = (c & 7) * 8;
      *(bf16x8*)(Ks + row * 72 + off) =
          *(const bf16x8*)(kv + (size_t)(b * N_ + kt * 64 + row) * 512 + hkv * 64 + off);
      *(bf16x8*)(Vs + row * 72 + off) =
          *(const bf16x8*)(vt + ((size_t)(b * HKV_ + hkv) * 64 + row) * N_ + kt * 64 + off);
    }
    __syncthreads();

    if (kt * 64 <= qrow0 + 31) {  // some row of this wave attends this k-tile
      // S = Q K^T (already scaled: q folded with gain/sqrt(D)/log2e)
      f32x4 s[2][4];
#pragma unroll
      for (int rt = 0; rt < 2; ++rt)
#pragma unroll
        for (int ct = 0; ct < 4; ++ct) s[rt][ct] = z;
#pragma unroll
      for (int kx = 0; kx < 2; ++kx) {
        bf16x8 kf[4];
#pragma unroll
        for (int ct = 0; ct < 4; ++ct)
          kf[ct] = *(const bf16x8*)(Ks + (ct * 16 + lr) * 72 + kx * 32 + quad * 8);
#pragma unroll
        for (int rt = 0; rt < 2; ++rt)
#pragma unroll
          for (int ct = 0; ct < 4; ++ct)
            s[rt][ct] = __builtin_amdgcn_mfma_f32_16x16x32_bf16(qf[rt][kx], kf[ct],
                                                                s[rt][ct], 0, 0, 0);
      }
      // Causal mask (only diagonal-crossing tiles)
      if (kt * 64 + 63 > qrow0) {
#pragma unroll
        for (int rt = 0; rt < 2; ++rt)
#pragma unroll
          for (int ct = 0; ct < 4; ++ct)
#pragma unroll
            for (int r = 0; r < 4; ++r) {
              int row = qrow0 + rt * 16 + quad * 4 + r;
              int col = kt * 64 + ct * 16 + lr;
              if (col > row) s[rt][ct][r] = NEGINF;
            }
      }
      // Online softmax per q-row (row = rt*16 + quad*4 + r)
#pragma unroll
      for (int rt = 0; rt < 2; ++rt) {
        float al[4];
#pragma unroll
        for (int r = 0; r < 4; ++r) {
          float mx = fmaxf(fmaxf(s[rt][0][r], s[rt][1][r]),
                           fmaxf(s[rt][2][r], s[rt][3][r]));
          mx = fmaxf(mx, __shfl_xor(mx, 1));
          mx = fmaxf(mx, __shfl_xor(mx, 2));
          mx = fmaxf(mx, __shfl_xor(mx, 4));
          mx = fmaxf(mx, __shfl_xor(mx, 8));
          float mnew = fmaxf(mrow[rt][r], mx);
          float alpha = exp2f(mrow[rt][r] - mnew);
          mrow[rt][r] = mnew;
          float rs = 0.f;
#pragma unroll
          for (int ct = 0; ct < 4; ++ct) {
            float p = exp2f(s[rt][ct][r] - mnew);
            s[rt][ct][r] = p;
            rs += p;
          }
          rs += __shfl_xor(rs, 1);
          rs += __shfl_xor(rs, 2);
          rs += __shfl_xor(rs, 4);
          rs += __shfl_xor(rs, 8);
          lrow[rt][r] = lrow[rt][r] * alpha + rs;
          al[r] = alpha;
        }
#pragma unroll
        for (int dt = 0; dt < 4; ++dt)
#pragma unroll
          for (int r = 0; r < 4; ++r) acc[rt][dt][r] *= al[r];
        // Write P (C-layout) to wave-private LDS rows
#pragma unroll
        for (int ct = 0; ct < 4; ++ct)
#pragma unroll
          for (int r = 0; r < 4; ++r)
            Ps[(wave * 32 + rt * 16 + quad * 4 + r) * 72 + ct * 16 + lr] =
                (bf16)s[rt][ct][r];
      }
      // Wave-local LDS write->read ordering (rows wave-private, guard
      // wave-uniform -> no __syncthreads needed, waitcnt only)
      asm volatile("s_waitcnt lgkmcnt(0)" ::: "memory");
      // O += P V  (P via A-layout reads from Ps; V^T rows give B-layout)
#pragma unroll
      for (int kx = 0; kx < 2; ++kx) {
        bf16x8 vf[4], pf[2];
#pragma unroll
        for (int dt = 0; dt < 4; ++dt)
          vf[dt] = *(const bf16x8*)(Vs + (dt * 16 + lr) * 72 + kx * 32 + quad * 8);
#pragma unroll
        for (int rt = 0; rt < 2; ++rt)
          pf[rt] = *(const bf16x8*)(Ps + (wave * 32 + rt * 16 + lr) * 72 + kx * 32 + quad * 8);
#pragma unroll
        for (int rt = 0; rt < 2; ++rt)
#pragma unroll
          for (int dt = 0; dt < 4; ++dt)
            acc[rt][dt] = __builtin_amdgcn_mfma_f32_16x16x32_bf16(pf[rt], vf[dt],
                                                                  acc[rt][dt], 0, 0, 0);
      }
    }
  }
  // Epilogue: y = O / l, written IN PLACE into this block's own q slice
#pragma unroll
  for (int rt = 0; rt < 2; ++rt)
#pragma unroll
    for (int dt = 0; dt < 4; ++dt)
#pragma unroll
      for (int r = 0; r < 4; ++r) {
        int row = qrow0 + rt * 16 + quad * 4 + r;
        q[((size_t)(b * N_ + row) * H_ + h) * D_ + dt * 16 + lr] =
            (bf16)(acc[rt][dt][r] / lrow[rt][r]);
      }
}

// ---------------------------------------------------------------------------
extern "C" void kernel_launch(void* const* d_in, const int* in_sizes, int n_in,
                              void* d_out, int out_size, void* d_ws, size_t ws_size,
                              hipStream_t stream) {
  // Inputs FP32 (device-verified round 8). OUTPUT FP32 (reference returns
  // float32; harness contract: "bfloat16 -> __hip_bfloat16*, else float*").
  const float* x = (const float*)d_in[0];
  const float* wq = (const float*)d_in[1];
  const float* wk = (const float*)d_in[2];
  const float* wv = (const float*)d_in[3];
  const float* wo = (const float*)d_in[4];
  float* out = (float*)d_out;  // 8388608 fp32 elements = 33.5 MB
  char* ws = (char*)d_ws;
  // ws (28 MB): q/y 16 MB [0,16M) | kv 8 MB [16M,24M) | vt 4 MB [24M,28M)
  bf16* q = (bf16*)(ws);
  bf16* kv = (bf16*)(ws + 16777216);
  bf16* vt = (bf16*)(ws + 25165824);

  // 1) projections: fp32 x * fp32 w -> bf16 (convert during LDS staging)
  gemm_any<float, bf16><<<dim3(64, 8), 256, 0, stream>>>(x, wq, q, 8192, 1024, 1024, 1024, 0);
  gemm_any<float, bf16><<<dim3(64, 2), 256, 0, stream>>>(x, wk, kv, 8192, 1024, 256, 512, 0);
  gemm_any<float, bf16><<<dim3(64, 2), 256, 0, stream>>>(x, wv, kv, 8192, 1024, 256, 512, 256);
  // 2) RMSNorm + RoPE (+ folded q scaling), in place
  norm_rope<<<dim3(40960), 256, 0, stream>>>(q, kv);
  // 3) V -> V^T per (b, hkv)
  transpose_v<<<dim3(32, 16), 256, 0, stream>>>(kv, vt);
  // 4) causal GQA flash attention, output in place into q
  attn<<<dim3(16, 16, 4), 256, 0, stream>>>(q, kv, vt);
  // 5) output projection: bf16 y * fp32 wo -> FP32 straight into d_out
  gemm_any<bf16, float><<<dim3(64, 8), 256, 0, stream>>>(q, wo, out, 8192, 1024, 1024, 1024, 0);
}

// Round 10
// 589.555 us; speedup vs baseline: 1.0919x; 1.0919x over previous
//
#include <hip/hip_runtime.h>

typedef __bf16 bf16;
typedef __bf16 bf16x8 __attribute__((ext_vector_type(8)));
typedef __bf16 bf16x4 __attribute__((ext_vector_type(4)));
typedef float f32x4 __attribute__((ext_vector_type(4)));

#define B_ 4
#define N_ 2048
#define C_ 1024
#define H_ 16
#define HKV_ 4
#define D_ 64

// fold: 1.5 (qk_gain) * 0.125 (1/sqrt(64)) * log2(e)  -> use exp2f in softmax
#define QSCALE 0.2705053201666806f
#define NEGINF (-1.0e30f)

// ---------------------------------------------------------------------------
// GEMM: C[M][.] = A[M][K] * B[K][.].
//   A: row-major, dtype AT (float -> converted to bf16 during LDS staging,
//      bf16 -> copied directly).
//   B: row-major FP32 with row stride bn_stride; transposed AND converted to
//      bf16 during LDS staging into Bs[n][k].
//   C: dtype OT (bf16 intermediates, float final), at [row*ostride+col0+col].
// 128x128 tile, BK=64, 4 waves x (64x64 quadrant) via 4x4 16x16x32 MFMAs.
template <typename AT, typename OT>
__global__ __launch_bounds__(256) void gemm_any(const AT* __restrict__ A,
                                                const float* __restrict__ B,
                                                OT* __restrict__ Cmat,
                                                int M, int K, int bn_stride,
                                                int ostride, int col0) {
  __shared__ __align__(16) bf16 As[128 * 72];
  __shared__ __align__(16) bf16 Bs[128 * 72];
  int m0 = blockIdx.x * 128, n0 = blockIdx.y * 128;
  int tid = threadIdx.x;
  int wave = tid >> 6, lane = tid & 63;
  int quad = lane >> 4, lr = lane & 15;
  int wr = (wave >> 1) * 64, wc = (wave & 1) * 64;

  f32x4 acc[4][4];
  const f32x4 z = {0.f, 0.f, 0.f, 0.f};
#pragma unroll
  for (int i = 0; i < 4; ++i)
#pragma unroll
    for (int j = 0; j < 4; ++j) acc[i][j] = z;

  for (int k0 = 0; k0 < K; k0 += 64) {
    __syncthreads();
    if constexpr (sizeof(AT) == 4) {
#pragma unroll
      for (int i = 0; i < 8; ++i) {
        int c = tid + i * 256;
        int row = c >> 4, off4 = (c & 15) * 4;
        f32x4 av = *(const f32x4*)(A + (size_t)(m0 + row) * K + k0 + off4);
        bf16x4 a16;
#pragma unroll
        for (int j = 0; j < 4; ++j) a16[j] = (bf16)av[j];
        *(bf16x4*)(As + row * 72 + off4) = a16;
      }
    } else {
#pragma unroll
      for (int i = 0; i < 4; ++i) {
        int c = tid + i * 256;
        int row = c >> 3, off = (c & 7) * 8;
        *(bf16x8*)(As + row * 72 + off) =
            *(const bf16x8*)(A + (size_t)(m0 + row) * K + k0 + off);
      }
    }
#pragma unroll
    for (int i = 0; i < 8; ++i) {
      int c = tid + i * 256;
      int k = c >> 5, n4 = (c & 31) * 4;
      f32x4 bv = *(const f32x4*)(B + (size_t)(k0 + k) * bn_stride + n0 + n4);
#pragma unroll
      for (int j = 0; j < 4; ++j) Bs[(n4 + j) * 72 + k] = (bf16)bv[j];
    }
    __syncthreads();
#pragma unroll
    for (int kx = 0; kx < 2; ++kx) {
      bf16x8 af[4], bfr[4];
#pragma unroll
      for (int t = 0; t < 4; ++t) {
        af[t] = *(const bf16x8*)(As + (wr + t * 16 + lr) * 72 + kx * 32 + quad * 8);
        bfr[t] = *(const bf16x8*)(Bs + (wc + t * 16 + lr) * 72 + kx * 32 + quad * 8);
      }
#pragma unroll
      for (int rt = 0; rt < 4; ++rt)
#pragma unroll
        for (int ct = 0; ct < 4; ++ct)
          acc[rt][ct] = __builtin_amdgcn_mfma_f32_16x16x32_bf16(af[rt], bfr[ct],
                                                                acc[rt][ct], 0, 0, 0);
    }
  }
#pragma unroll
  for (int rt = 0; rt < 4; ++rt)
#pragma unroll
    for (int ct = 0; ct < 4; ++ct)
#pragma unroll
      for (int r = 0; r < 4; ++r) {
        int row = m0 + wr + rt * 16 + quad * 4 + r;
        int col = col0 + n0 + wc + ct * 16 + lr;
        Cmat[(size_t)row * ostride + col] = (OT)acc[rt][ct][r];
      }
}

// ---------------------------------------------------------------------------
// V transpose: kv [B*N][512] (v = cols 256..511, head hkv at 256+hkv*64)
//           -> vt [B][HKV][D][N]
__global__ __launch_bounds__(256) void transpose_v(const bf16* __restrict__ kv,
                                                   bf16* __restrict__ vt) {
  __shared__ __align__(16) bf16 lds[64 * 72];
  int nt = blockIdx.x;
  int bh = blockIdx.y;
  int b = bh >> 2, hkv = bh & 3;
  int tid = threadIdx.x;
#pragma unroll
  for (int i = 0; i < 2; ++i) {
    int c = tid + i * 256;
    int tok = c >> 3, off = (c & 7) * 8;
    *(bf16x8*)(lds + tok * 72 + off) =
        *(const bf16x8*)(kv + (size_t)(b * N_ + nt * 64 + tok) * 512 + 256 + hkv * 64 + off);
  }
  __syncthreads();
#pragma unroll
  for (int i = 0; i < 2; ++i) {
    int c = tid + i * 256;
    int d = c >> 3, toff = (c & 7) * 8;
    bf16x8 tv;
#pragma unroll
    for (int j = 0; j < 8; ++j) tv[j] = lds[(toff + j) * 72 + d];
    *(bf16x8*)(vt + ((size_t)bh * 64 + d) * N_ + nt * 64 + toff) = tv;
  }
}

// ---------------------------------------------------------------------------
// Per-head RMSNorm + RoPE, in place (bf16 data, fp32 math). One wave per
// (token, head) 64-vector. q heads get folded QSCALE; k heads don't.
__global__ __launch_bounds__(256) void norm_rope(bf16* __restrict__ q,
                                                 bf16* __restrict__ kv) {
  int wave = threadIdx.x >> 6, lane = threadIdx.x & 63;
  int hid = blockIdx.x * 4 + wave;
  int t = hid / 20;
  int sub = hid - t * 20;
  int n = t & (N_ - 1);
  bf16* ptr;
  float oscale;
  if (sub < 16) {
    ptr = q + ((size_t)t * 16 + sub) * 64;
    oscale = QSCALE;
  } else {
    ptr = kv + (size_t)t * 512 + (sub - 16) * 64;
    oscale = 1.0f;
  }
  float x = (float)ptr[lane];
  float ss = x * x;
  ss += __shfl_xor(ss, 1);
  ss += __shfl_xor(ss, 2);
  ss += __shfl_xor(ss, 4);
  ss += __shfl_xor(ss, 8);
  ss += __shfl_xor(ss, 16);
  ss += __shfl_xor(ss, 32);
  float rn = rsqrtf(ss * (1.0f / 64.0f) + 1.1920929e-07f);
  float xn = x * rn;
  float pr = __shfl_xor(xn, 32);
  float rot = (lane < 32) ? -pr : pr;
  float ang = (float)n * exp2f(-0.41524101186092029f * (float)(lane & 31));
  float sv, cv;
  sincosf(ang, &sv, &cv);
  ptr[lane] = (bf16)((xn * cv + rot * sv) * oscale);
}

// ---------------------------------------------------------------------------
// Causal flash attention with GQA — TRANSPOSED dataflow (S^T / O^T).
//   S^T = K·Q^T   (A = K from Ks[key][d],  B = Q^T via q[qrow][d] loads)
//   O^T = V^T·P^T (A = V^T from Vs[d][key], B = P^T via Ps[qrow][key] loads)
// In S^T's C-layout the q-row is the COLUMN (= lane&15): softmax state m/l
// is a per-lane scalar, reductions are in-register + 2 shuffles (xor 16,32),
// P^T writes are b64 vectors, epilogue is b64 stores. Output in place into q
// (each block touches only its own disjoint (rows, head) slice).
// blockIdx.x is REVERSED onto qt so long (late-qt) blocks dispatch first.
__global__ __launch_bounds__(256) void attn(bf16* __restrict__ q,
                                            const bf16* __restrict__ kv,
                                            const bf16* __restrict__ vt) {
  __shared__ __align__(16) bf16 Ks[64 * 72];   // [key][d]
  __shared__ __align__(16) bf16 Vs[64 * 72];   // [d][key]
  __shared__ __align__(16) bf16 Ps[128 * 72];  // [q-row][key], wave-private rows
  int qt = 15 - blockIdx.x;  // load balance: longest blocks first
  int h = blockIdx.y, b = blockIdx.z;
  int hkv = h >> 2;
  int tid = threadIdx.x;
  int wave = tid >> 6, lane = tid & 63;
  int quad = lane >> 4, lr = lane & 15;
  int qrow0 = qt * 128 + wave * 32;

  // Q fragments (serve as B-operand = Q^T): lane holds Q[qrow0+rt*16+lr][kx*32+quad*8..]
  bf16x8 qf[2][2];
#pragma unroll
  for (int rt = 0; rt < 2; ++rt)
#pragma unroll
    for (int kx = 0; kx < 2; ++kx)
      qf[rt][kx] = *(const bf16x8*)(
          q + ((size_t)(b * N_ + qrow0 + rt * 16 + lr) * H_ + h) * D_ + kx * 32 + quad * 8);

  f32x4 acc[2][4];  // acc[rt][dt] = O^T tile: row d=dt*16+quad*4+r, col qrow=rt*16+lr
  const f32x4 z = {0.f, 0.f, 0.f, 0.f};
  float m_i[2], l_i[2];  // per-lane scalars (q-row = qrow0 + rt*16 + lr)
#pragma unroll
  for (int rt = 0; rt < 2; ++rt) {
#pragma unroll
    for (int dt = 0; dt < 4; ++dt) acc[rt][dt] = z;
    m_i[rt] = NEGINF;
    l_i[rt] = 0.f;
  }

  int nkt = qt * 2 + 2;
  for (int kt = 0; kt < nkt; ++kt) {
    __syncthreads();
#pragma unroll
    for (int i = 0; i < 2; ++i) {
      int c = tid + i * 256;
      int row = c >> 3, off = (c & 7) * 8;
      *(bf16x8*)(Ks + row * 72 + off) =
          *(const bf16x8*)(kv + (size_t)(b * N_ + kt * 64 + row) * 512 + hkv * 64 + off);
      *(bf16x8*)(Vs + row * 72 + off) =
          *(const bf16x8*)(vt + ((size_t)(b * HKV_ + hkv) * 64 + row) * N_ + kt * 64 + off);
    }
    __syncthreads();

    if (kt * 64 <= qrow0 + 31) {
      // S^T = K·Q^T: st[rt][ct] — key = kt*64 + ct*16 + quad*4 + r, qrow col = lr
      f32x4 st[2][4];
#pragma unroll
      for (int rt = 0; rt < 2; ++rt)
#pragma unroll
        for (int ct = 0; ct < 4; ++ct) st[rt][ct] = z;
#pragma unroll
      for (int kx = 0; kx < 2; ++kx) {
        bf16x8 kf[4];
#pragma unroll
        for (int ct = 0; ct < 4; ++ct)
          kf[ct] = *(const bf16x8*)(Ks + (ct * 16 + lr) * 72 + kx * 32 + quad * 8);
#pragma unroll
        for (int rt = 0; rt < 2; ++rt)
#pragma unroll
          for (int ct = 0; ct < 4; ++ct)
            st[rt][ct] = __builtin_amdgcn_mfma_f32_16x16x32_bf16(kf[ct], qf[rt][kx],
                                                                 st[rt][ct], 0, 0, 0);
      }
      // Causal mask (diagonal-crossing tiles only): mask key > qrow
      if (kt * 64 + 63 > qrow0) {
#pragma unroll
        for (int rt = 0; rt < 2; ++rt) {
          int qrow = qrow0 + rt * 16 + lr;
#pragma unroll
          for (int ct = 0; ct < 4; ++ct)
#pragma unroll
            for (int r = 0; r < 4; ++r) {
              int key = kt * 64 + ct * 16 + quad * 4 + r;
              if (key > qrow) st[rt][ct][r] = NEGINF;
            }
        }
      }
      // Online softmax: per-lane scalar state, 2+2 shuffles total per rt
#pragma unroll
      for (int rt = 0; rt < 2; ++rt) {
        float mx = NEGINF;
#pragma unroll
        for (int ct = 0; ct < 4; ++ct)
#pragma unroll
          for (int r = 0; r < 4; ++r) mx = fmaxf(mx, st[rt][ct][r]);
        mx = fmaxf(mx, __shfl_xor(mx, 16));
        mx = fmaxf(mx, __shfl_xor(mx, 32));
        float mnew = fmaxf(m_i[rt], mx);
        float alpha = exp2f(m_i[rt] - mnew);
        m_i[rt] = mnew;
        float rs = 0.f;
#pragma unroll
        for (int ct = 0; ct < 4; ++ct)
#pragma unroll
          for (int r = 0; r < 4; ++r) {
            float p = exp2f(st[rt][ct][r] - mnew);
            st[rt][ct][r] = p;
            rs += p;
          }
        rs += __shfl_xor(rs, 16);
        rs += __shfl_xor(rs, 32);
        l_i[rt] = l_i[rt] * alpha + rs;
#pragma unroll
        for (int dt = 0; dt < 4; ++dt)
#pragma unroll
          for (int r = 0; r < 4; ++r) acc[rt][dt][r] *= alpha;
        // P^T -> Ps[qrow][key]: b64 vector writes (keys quad*4+r contiguous)
#pragma unroll
        for (int ct = 0; ct < 4; ++ct) {
          bf16x4 pk;
#pragma unroll
          for (int r = 0; r < 4; ++r) pk[r] = (bf16)st[rt][ct][r];
          *(bf16x4*)(Ps + (wave * 32 + rt * 16 + lr) * 72 + ct * 16 + quad * 4) = pk;
        }
      }
      // Wave-local LDS ordering (rows wave-private, guard wave-uniform)
      asm volatile("s_waitcnt lgkmcnt(0)" ::: "memory");
      // O^T += V^T·P^T
#pragma unroll
      for (int kx = 0; kx < 2; ++kx) {
        bf16x8 vf[4], pf[2];
#pragma unroll
        for (int dt = 0; dt < 4; ++dt)
          vf[dt] = *(const bf16x8*)(Vs + (dt * 16 + lr) * 72 + kx * 32 + quad * 8);
#pragma unroll
        for (int rt = 0; rt < 2; ++rt)
          pf[rt] = *(const bf16x8*)(Ps + (wave * 32 + rt * 16 + lr) * 72 + kx * 32 + quad * 8);
#pragma unroll
        for (int rt = 0; rt < 2; ++rt)
#pragma unroll
          for (int dt = 0; dt < 4; ++dt)
            acc[rt][dt] = __builtin_amdgcn_mfma_f32_16x16x32_bf16(vf[dt], pf[rt],
                                                                  acc[rt][dt], 0, 0, 0);
      }
    }
  }
  // Epilogue: y = O / l — O^T layout => lane owns q-row (rt, lr), d = dt*16+quad*4+r
#pragma unroll
  for (int rt = 0; rt < 2; ++rt) {
    float inv = 1.0f / l_i[rt];
    int qrow = qrow0 + rt * 16 + lr;
#pragma unroll
    for (int dt = 0; dt < 4; ++dt) {
      bf16x4 ov;
#pragma unroll
      for (int r = 0; r < 4; ++r) ov[r] = (bf16)(acc[rt][dt][r] * inv);
      *(bf16x4*)(q + ((size_t)(b * N_ + qrow) * H_ + h) * D_ + dt * 16 + quad * 4) = ov;
    }
  }
}

// ---------------------------------------------------------------------------
extern "C" void kernel_launch(void* const* d_in, const int* in_sizes, int n_in,
                              void* d_out, int out_size, void* d_ws, size_t ws_size,
                              hipStream_t stream) {
  // Inputs FP32; output FP32 (verified round 9). Intermediates bf16.
  const float* x = (const float*)d_in[0];
  const float* wq = (const float*)d_in[1];
  const float* wk = (const float*)d_in[2];
  const float* wv = (const float*)d_in[3];
  const float* wo = (const float*)d_in[4];
  float* out = (float*)d_out;
  char* ws = (char*)d_ws;
  // ws (28 MB): q/y 16 MB [0,16M) | kv 8 MB [16M,24M) | vt 4 MB [24M,28M)
  bf16* q = (bf16*)(ws);
  bf16* kv = (bf16*)(ws + 16777216);
  bf16* vt = (bf16*)(ws + 25165824);

  gemm_any<float, bf16><<<dim3(64, 8), 256, 0, stream>>>(x, wq, q, 8192, 1024, 1024, 1024, 0);
  gemm_any<float, bf16><<<dim3(64, 2), 256, 0, stream>>>(x, wk, kv, 8192, 1024, 256, 512, 0);
  gemm_any<float, bf16><<<dim3(64, 2), 256, 0, stream>>>(x, wv, kv, 8192, 1024, 256, 512, 256);
  norm_rope<<<dim3(40960), 256, 0, stream>>>(q, kv);
  transpose_v<<<dim3(32, 16), 256, 0, stream>>>(kv, vt);
  attn<<<dim3(16, 16, 4), 256, 0, stream>>>(q, kv, vt);
  gemm_any<bf16, float><<<dim3(64, 8), 256, 0, stream>>>(q, wo, out, 8192, 1024, 1024, 1024, 0);
}